// Round 10
// baseline (217.019 us; speedup 1.0000x reference)
//
#include <hip/hip_runtime.h>
#include <hip/hip_fp16.h>

// Problem: inputs (8, 64, 16, 32, 32) fp32, embedding (1024, 64) fp32
#define THW    16384
#define NTOT   131072
#define KDIM   1024
#define CDIM   64
#define QELEMS 8388608          // 8*64*16*32*32
#define LOSS_OFF 8388608
#define IDX_OFF  8388610
#define BN     32               // queries per block (ONE wave)

typedef _Float16 half8   __attribute__((ext_vector_type(8)));
typedef _Float16 half4_t __attribute__((ext_vector_type(4)));
typedef float    f32x4   __attribute__((ext_vector_type(4)));

// ---- prep: zero losses; split E into fp16 hi/lo (lo scaled 2^12) into ONE
// interleaved buffer Ef[tile][slot][lane][8], slots = {h.ch0, h.ch1, l.ch0,
// l.ch1}; tile = 4 KB laid out so lane's fragment is bytes lane*16 at slot
// offsets 0/1024/2048/3072 — loadable per-lane with coalesced dwordx4.
// me2h[row] = -0.5*||e||^2 (hh-chain seed, read per-tile from L2 by vq_main).
__global__ __launch_bounds__(256) void vq_prep(const float* __restrict__ emb,
        _Float16* __restrict__ Ef, float* __restrict__ me2h,
        float* __restrict__ out) {
    const int t = threadIdx.x;
    if (blockIdx.x == 0 && t == 0) { out[LOSS_OFF] = 0.f; out[LOSS_OFF + 1] = 0.f; }
    const int ln   = t >> 4;
    const int g    = t & 15;
    const int tile = blockIdx.x;
    const int row  = tile * 16 + ln;
    const int c0   = g * 4;
    float4 v = *(const float4*)(emb + (size_t)row * CDIM + c0);
    const float xs[4] = {v.x, v.y, v.z, v.w};
    half4_t h, l;
    float s = 0.f;
    #pragma unroll
    for (int j = 0; j < 4; ++j) {
        const _Float16 hj = (_Float16)xs[j];
        const _Float16 lj = (_Float16)((xs[j] - (float)hj) * 4096.0f);
        h[j] = hj; l[j] = lj;
        s = fmaf(xs[j], xs[j], s);
    }
    const int ch = c0 >> 5;
    const int lq = (c0 & 31) >> 3;
    const int j0 = c0 & 7;
    const int fl = lq * 16 + ln;
    *(half4_t*)(Ef + (((size_t)tile * 4 + ch)     * 64 + fl) * 8 + j0) = h;
    *(half4_t*)(Ef + (((size_t)tile * 4 + 2 + ch) * 64 + fl) * 8 + j0) = l;
    #pragma unroll
    for (int off = 1; off < 16; off <<= 1) s += __shfl_xor(s, off, 64);
    if (g == 0) me2h[row] = -0.5f * s;
}

// ---- main: SINGLE-WAVE blocks, REGISTER-staged A-tiles. The hot loop has
// ZERO LDS ops, ZERO barriers, ZERO inline asm: each tile's fragments are
// loaded straight to VGPRs (4 coalesced dwordx4 + 1 e2 dwordx4), 3 named
// register buffers rotate with compile-time indices, and the COMPILER
// inserts the counted vmcnt waits (no manual counting, spill-safe).
// 12 independent self-paced waves/CU -> time-averaged pipe demand.
__global__ __launch_bounds__(64, 3) void vq_main(const float* __restrict__ in,
        const float* __restrict__ emb,
        const _Float16* __restrict__ Ef,
        const float* __restrict__ me2h, float* __restrict__ out) {

    __shared__ char smem[8832];
    // X phase:   Xs[32][68] @ 0 (8704 B)
    // epilogue:  Q[32][68] @ 0 (8704 B), idxs @ 8704 (128 B)
    float (*Xs)[68] = (float (*)[68])smem;
    float (*Q)[68]  = (float (*)[68])smem;
    int* idxs = (int*)(smem + 8704);

    const int lane = threadIdx.x & 63;
    const int ln   = lane & 15;
    const int lq   = lane >> 4;

    const int n0   = blockIdx.x * BN;
    const int bb   = n0 >> 14;
    const int thw0 = n0 & (THW - 1);
    const float* inb = in  + (size_t)bb * CDIM * THW + thw0;
    float*      outb = out + (size_t)bb * CDIM * THW + thw0;

    // ---- stage X tile ([n][c] transpose); 32 queries x 64 channels ----
    {
        const int nl = lane & 31;
        const int hf = lane >> 5;
        #pragma unroll 8
        for (int r = 0; r < 32; ++r) {
            const int c = hf * 32 + r;
            Xs[nl][c] = inb[(size_t)c * THW + nl];
        }
    }
    __syncthreads();    // single wave: cheap lgkmcnt drain, ironclad ordering

    // ---- B fragments (fp16 hi/lo) + ||x||^2 in registers: 2 qg groups ----
    half8 Bh[2][2], Bl[2][2];
    float x2r[2];
    #pragma unroll
    for (int qg = 0; qg < 2; ++qg) {
        const int q = qg * 16 + ln;
        float s = 0.f;
        #pragma unroll
        for (int ch = 0; ch < 2; ++ch) {
            const float* xp = &Xs[q][ch * 32 + lq * 8];
            const float4 xa = *(const float4*)(xp);
            const float4 xb = *(const float4*)(xp + 4);
            const float xv[8] = {xa.x, xa.y, xa.z, xa.w, xb.x, xb.y, xb.z, xb.w};
            #pragma unroll
            for (int j = 0; j < 8; ++j) {
                const _Float16 h = (_Float16)xv[j];
                const _Float16 l = (_Float16)((xv[j] - (float)h) * 4096.0f);
                Bh[qg][ch][j] = h;
                Bl[qg][ch][j] = l;
                s = fmaf(xv[j], xv[j], s);
            }
        }
        s += __shfl_xor(s, 16, 64);     // fold the 4 lq-quads: full ||x||^2
        s += __shfl_xor(s, 32, 64);
        x2r[qg] = s;
    }

    const float* e2g = me2h + lq * 4;

    float bests[2] = {-3.4e38f, -3.4e38f};
    int   besti[2] = {0, 0};

// load tile T's fragments straight to registers (4 x coalesced dwordx4:
// each instruction reads 64 lanes x 16 B = 1 KB contiguous) + e2 seed.
#define LOADT(T, A0, A1, A2, A3, ER)                                          \
    {   const half8* g = (const half8*)((const char*)Ef + (size_t)(T) * 4096); \
        A0 = g[lane];       A1 = g[64 + lane];                                \
        A2 = g[128 + lane]; A3 = g[192 + lane];                               \
        ER = *(const f32x4*)(e2g + (size_t)(T) * 16);                         \
    }

#define COMP(T, A0, A1, A2, A3, E2)                                           \
    {   const int kb = (T) * 16;                                              \
        __builtin_amdgcn_s_setprio(1);                                        \
        _Pragma("unroll")                                                     \
        for (int qg = 0; qg < 2; ++qg) {                                      \
            f32x4 hh = (E2);                                                  \
            hh = __builtin_amdgcn_mfma_f32_16x16x32_f16((A0), Bh[qg][0], hh, 0, 0, 0); \
            hh = __builtin_amdgcn_mfma_f32_16x16x32_f16((A1), Bh[qg][1], hh, 0, 0, 0); \
            f32x4 cr = {0.f, 0.f, 0.f, 0.f};                                  \
            cr = __builtin_amdgcn_mfma_f32_16x16x32_f16((A0), Bl[qg][0], cr, 0, 0, 0); \
            cr = __builtin_amdgcn_mfma_f32_16x16x32_f16((A2), Bh[qg][0], cr, 0, 0, 0); \
            cr = __builtin_amdgcn_mfma_f32_16x16x32_f16((A1), Bl[qg][1], cr, 0, 0, 0); \
            cr = __builtin_amdgcn_mfma_f32_16x16x32_f16((A3), Bh[qg][1], cr, 0, 0, 0); \
            _Pragma("unroll")                                                 \
            for (int r = 0; r < 4; ++r) {                                     \
                const float cv = fmaf(2.44140625e-4f, cr[r], hh[r]);          \
                if (cv > bests[qg]) { bests[qg] = cv; besti[qg] = kb + r; }    \
            }                                                                 \
        }                                                                     \
        __builtin_amdgcn_s_setprio(0);                                        \
    }

    // 3 named register buffers (compile-time indices), depth-2 prefetch:
    // issue tile t+2's loads, compute tile t. Compiler inserts the waits.
    half8 pa0, pa1, pa2, pa3, pb0, pb1, pb2, pb3, pc0, pc1, pc2, pc3;
    f32x4 ea, eb, ec;
    LOADT(0, pa0, pa1, pa2, pa3, ea)
    LOADT(1, pb0, pb1, pb2, pb3, eb)
    #pragma unroll 1
    for (int t0 = 0; t0 < 60; t0 += 3) {
        LOADT(t0 + 2, pc0, pc1, pc2, pc3, ec) COMP(t0,     pa0, pa1, pa2, pa3, ea)
        LOADT(t0 + 3, pa0, pa1, pa2, pa3, ea) COMP(t0 + 1, pb0, pb1, pb2, pb3, eb)
        LOADT(t0 + 4, pb0, pb1, pb2, pb3, eb) COMP(t0 + 2, pc0, pc1, pc2, pc3, ec)
    }
    // after loop: pa=tile60, pb=tile61 (seeds ea, eb)
    LOADT(62, pc0, pc1, pc2, pc3, ec) COMP(60, pa0, pa1, pa2, pa3, ea)
    LOADT(63, pa0, pa1, pa2, pa3, ea) COMP(61, pb0, pb1, pb2, pb3, eb)
    COMP(62, pc0, pc1, pc2, pc3, ec)
    COMP(63, pa0, pa1, pa2, pa3, ea)

    besti[0] += lq * 4;     // full code index = T*16 + lq*4 + r
    besti[1] += lq * 4;

    // ---- wave-internal argmax reduce across the 4 row-quads ----
    #pragma unroll
    for (int qg = 0; qg < 2; ++qg) {
        #pragma unroll
        for (int msk = 16; msk <= 32; msk <<= 1) {
            const float ov = __shfl_xor(bests[qg], msk, 64);
            const int   oi = __shfl_xor(besti[qg], msk, 64);
            if (ov > bests[qg] || (ov == bests[qg] && oi < besti[qg])) {
                bests[qg] = ov; besti[qg] = oi;
            }
        }
    }

    // ---- idx + loss straight from registers ----
    float lsum = 0.f;
    if (lq == 0) {
        #pragma unroll
        for (int qg = 0; qg < 2; ++qg) {
            const int q = qg * 16 + ln;
            idxs[q] = besti[qg];
            out[IDX_OFF + n0 + q] = (float)besti[qg];
            // d = -2*s ; loss term = d + ||x||^2
            lsum += fmaf(-2.0f, bests[qg], x2r[qg]);
        }
    }
    #pragma unroll
    for (int off = 32; off > 0; off >>= 1) lsum += __shfl_down(lsum, off, 64);
    if (lane == 0) {
        atomicAdd(&out[LOSS_OFF],     lsum * (1.0f  / (float)QELEMS));
        atomicAdd(&out[LOSS_OFF + 1], lsum * (0.25f / (float)QELEMS));
    }
    __syncthreads();    // idxs visible (cheap: single wave)

    // ---- epilogue: gather code rows into LDS, transpose-write ----
    {
        const int q  = lane >> 1;
        const int hf = lane & 1;
        const float* er = emb + (size_t)idxs[q] * CDIM + hf * 32;
        #pragma unroll
        for (int j = 0; j < 8; ++j) {
            const float4 v = *(const float4*)(er + 4 * j);
            *(float4*)(&Q[q][hf * 32 + 4 * j]) = v;
        }
    }
    __syncthreads();    // Q visible (cheap: single wave)
    {
        const int nl = lane & 31;
        const int cb = lane >> 5;
        #pragma unroll 8
        for (int r = 0; r < 32; ++r) {
            const int c = 2 * r + cb;
            outb[(size_t)c * THW + nl] = Q[nl][c];
        }
    }
#undef LOADT
#undef COMP
}

extern "C" void kernel_launch(void* const* d_in, const int* in_sizes, int n_in,
                              void* d_out, int out_size, void* d_ws, size_t ws_size,
                              hipStream_t stream) {
    const float* in  = (const float*)d_in[0];   // (8, 64, 16, 32, 32) fp32
    const float* emb = (const float*)d_in[1];   // (1024, 64) fp32
    float* out = (float*)d_out;
    _Float16* Ef   = (_Float16*)d_ws;                       // 64 tiles * 4 KB = 256 KB
    float*    me2h = (float*)((char*)d_ws + 262144);        // 1024 floats = -0.5*||e||^2

    vq_prep<<<KDIM / 16, 256, 0, stream>>>(emb, Ef, me2h, out);
    vq_main<<<NTOT / BN, 64, 0, stream>>>(in, emb, Ef, me2h, out);
}

// Round 12
// 138.341 us; speedup vs baseline: 1.5687x; 1.5687x over previous
//
#include <hip/hip_runtime.h>
#include <hip/hip_fp16.h>

// Problem: inputs (8, 64, 16, 32, 32) fp32, embedding (1024, 64) fp32
#define THW    16384
#define NTOT   131072
#define KDIM   1024
#define CDIM   64
#define QELEMS 8388608          // 8*64*16*32*32
#define LOSS_OFF 8388608
#define IDX_OFF  8388610
#define BN     128              // queries per block

typedef _Float16 half8   __attribute__((ext_vector_type(8)));
typedef _Float16 half4_t __attribute__((ext_vector_type(4)));
typedef float    f32x4   __attribute__((ext_vector_type(4)));

// ---- prep: zero losses; split E into fp16 hi/lo (lo scaled 2^12) into ONE
// interleaved buffer Ef[tile][slot][lane][8], slots = {h.ch0, h.ch1, l.ch0,
// l.ch1}; tile = 4 KB, linear in the exact lane order vq_main's ds_reads use,
// so global_load_lds (wave-uniform base + lane*16) can stage it untouched.
// me2h[row] = -0.5*||e||^2 (seeds the hh MFMA chain; staged to LDS by main).
__global__ __launch_bounds__(256) void vq_prep(const float* __restrict__ emb,
        _Float16* __restrict__ Ef, float* __restrict__ me2h,
        float* __restrict__ out) {
    const int t = threadIdx.x;
    if (blockIdx.x == 0 && t == 0) { out[LOSS_OFF] = 0.f; out[LOSS_OFF + 1] = 0.f; }
    const int ln   = t >> 4;
    const int g    = t & 15;
    const int tile = blockIdx.x;
    const int row  = tile * 16 + ln;
    const int c0   = g * 4;
    float4 v = *(const float4*)(emb + (size_t)row * CDIM + c0);
    const float xs[4] = {v.x, v.y, v.z, v.w};
    half4_t h, l;
    float s = 0.f;
    #pragma unroll
    for (int j = 0; j < 4; ++j) {
        const _Float16 hj = (_Float16)xs[j];
        const _Float16 lj = (_Float16)((xs[j] - (float)hj) * 4096.0f);
        h[j] = hj; l[j] = lj;
        s = fmaf(xs[j], xs[j], s);
    }
    const int ch = c0 >> 5;
    const int lq = (c0 & 31) >> 3;
    const int j0 = c0 & 7;
    const int fl = lq * 16 + ln;
    *(half4_t*)(Ef + (((size_t)tile * 4 + ch)     * 64 + fl) * 8 + j0) = h;
    *(half4_t*)(Ef + (((size_t)tile * 4 + 2 + ch) * 64 + fl) * 8 + j0) = l;
    #pragma unroll
    for (int off = 1; off < 16; off <<= 1) s += __shfl_xor(s, off, 64);
    if (g == 0) me2h[row] = -0.5f * s;
}

// ---- main: r6 structure (2x2 wave split, counted-vmcnt) + register
// prefetch: 4 x 8 KB stage buffers (depth-3) so tile S+1's fragments are
// ds_read into the alternate register set DURING step S's MFMAs. Cross
// chain split into two 2-dep chains. e2 stays in LDS (lgkm domain; never
// mix compiler VMEM into the hand-counted vmcnt window — r10 lesson).
// __launch_bounds__(256,3): VGPR budget 168 — the double fragment set +
// Bh/Bl[4][2] needs ~140 VGPR; at (256,4)'s 128-cap it spills in the hot
// loop (r11 death). 3 blocks/CU is perf-neutral (r4 vs r5: 67.6 vs 67.7).
__global__ __launch_bounds__(256, 3) void vq_main(const float* __restrict__ in,
        const float* __restrict__ emb,
        const _Float16* __restrict__ Ef,
        const float* __restrict__ me2h, float* __restrict__ out) {

    __shared__ char smem[36864];
    // phase 1: Xs[128][68] @ 0 (34816 B)
    // loop:    buf0..3 @ 0/8192/16384/24576 (8 KB each); me2l @ 32768 (4 KB)
    // post:    bv @ 0 (512), bj @ 512, idxs @ 1024, wsum @ 1536,
    //          Q[128][68] @ 2048 (ends 36864) — all after the loop is dead
    float (*Xs)[68] = (float (*)[68])smem;
    float (*Q)[68]  = (float (*)[68])(smem + 2048);
    float* bv   = (float*)smem;
    int*   bj   = (int*)(smem + 512);
    int*   idxs = (int*)(smem + 1024);
    float* wsum = (float*)(smem + 1536);
    const char* me2l = (const char*)smem + 32768;

    const int tid  = threadIdx.x;
    const int lane = tid & 63;
    const int w    = tid >> 6;
    const int wk   = w & 1;         // tile parity this wave computes
    const int wq   = w >> 1;        // query half this wave computes
    const int ln   = lane & 15;
    const int lq   = lane >> 4;

    const int n0   = blockIdx.x * BN;
    const int bb   = n0 >> 14;
    const int thw0 = n0 & (THW - 1);
    const float* inb = in  + (size_t)bb * CDIM * THW + thw0;
    float*      outb = out + (size_t)bb * CDIM * THW + thw0;

    // ---- stage X tile ([n][c] transpose) ----
    {
        const int nl = tid & 127;
        const int hf = tid >> 7;
        #pragma unroll 8
        for (int r = 0; r < 32; ++r) {
            const int c = hf * 32 + r;
            Xs[nl][c] = inb[(size_t)c * THW + nl];
        }
    }
    __syncthreads();

    // ---- B fragments (fp16 hi/lo) + ||x||^2 in registers: 4 qg groups ----
    half8 Bh[4][2], Bl[4][2];
    float x2r[4];
    #pragma unroll
    for (int qg = 0; qg < 4; ++qg) {
        const int q = wq * 64 + qg * 16 + ln;
        float s = 0.f;
        #pragma unroll
        for (int ch = 0; ch < 2; ++ch) {
            const float* xp = &Xs[q][ch * 32 + lq * 8];
            const float4 xa = *(const float4*)(xp);
            const float4 xb = *(const float4*)(xp + 4);
            const float xv[8] = {xa.x, xa.y, xa.z, xa.w, xb.x, xb.y, xb.z, xb.w};
            #pragma unroll
            for (int j = 0; j < 8; ++j) {
                const _Float16 h = (_Float16)xv[j];
                const _Float16 l = (_Float16)((xv[j] - (float)h) * 4096.0f);
                Bh[qg][ch][j] = h;
                Bl[qg][ch][j] = l;
                s = fmaf(xv[j], xv[j], s);
            }
        }
        s += __shfl_xor(s, 16, 64);     // fold the 4 lq-quads: full ||x||^2
        s += __shfl_xor(s, 32, 64);
        x2r[qg] = s;
    }
    __syncthreads();    // Xs dead -> smem becomes bufs + me2l

    // me2 -> LDS (4 KB, one 16B chunk per thread); first op in vmcnt ledger
    __builtin_amdgcn_global_load_lds(
        (const unsigned int*)((const char*)me2h + w * 1024 + lane * 16),
        (unsigned int*)(smem + 32768 + w * 1024), 16, 0, 0);

    const char* Efb = (const char*)Ef + (size_t)(w * 1024 + lane * 16);

    float bests[4] = {-3.4e38f, -3.4e38f, -3.4e38f, -3.4e38f};
    int   besti[4] = {0, 0, 0, 0};

// stage tile-pair K (8 KB, cooperative: wave w writes its 1 KB slices)
#define STAGE(K, BI)                                                          \
    {   const char* gsrc = Efb + (size_t)(K) * 8192;                          \
        char* ldst = smem + (BI) * 8192 + w * 1024;                           \
        __builtin_amdgcn_global_load_lds((const unsigned int*)(gsrc),         \
                (unsigned int*)(ldst), 16, 0, 0);                             \
        __builtin_amdgcn_global_load_lds((const unsigned int*)(gsrc + 4096),  \
                (unsigned int*)(ldst + 4096), 16, 0, 0);                      \
    }

// ds_read tile KT's fragments (my wk parity) from buffer BI into registers,
// plus its e2 seed from me2l (lgkm domain; compiler manages the waits)
#define PREF(KT, BI, F0, F1, F2, F3, ER)                                      \
    {   const half8* A = (const half8*)(smem + (BI) * 8192 + wk * 4096);      \
        F0 = A[lane];       F1 = A[64 + lane];                                \
        F2 = A[128 + lane]; F3 = A[192 + lane];                               \
        ER = *(const f32x4*)(me2l + (KT) * 64 + lq * 16);                     \
    }

// compute tile KT from registers: per qg, hh (2-dep) || crA (2-dep) ||
// crB (2-dep); fold combines crA+crB with one extra add
#define COMP(KT, F0, F1, F2, F3, E2)                                          \
    {   const int kb = (KT) * 16;                                             \
        __builtin_amdgcn_s_setprio(1);                                        \
        _Pragma("unroll")                                                     \
        for (int qg = 0; qg < 4; ++qg) {                                      \
            f32x4 hh = (E2);                                                  \
            hh = __builtin_amdgcn_mfma_f32_16x16x32_f16((F0), Bh[qg][0], hh, 0, 0, 0); \
            hh = __builtin_amdgcn_mfma_f32_16x16x32_f16((F1), Bh[qg][1], hh, 0, 0, 0); \
            f32x4 crA = {0.f, 0.f, 0.f, 0.f};                                 \
            crA = __builtin_amdgcn_mfma_f32_16x16x32_f16((F0), Bl[qg][0], crA, 0, 0, 0); \
            crA = __builtin_amdgcn_mfma_f32_16x16x32_f16((F1), Bl[qg][1], crA, 0, 0, 0); \
            f32x4 crB = {0.f, 0.f, 0.f, 0.f};                                 \
            crB = __builtin_amdgcn_mfma_f32_16x16x32_f16((F2), Bh[qg][0], crB, 0, 0, 0); \
            crB = __builtin_amdgcn_mfma_f32_16x16x32_f16((F3), Bh[qg][1], crB, 0, 0, 0); \
            _Pragma("unroll")                                                 \
            for (int r = 0; r < 4; ++r) {                                     \
                const float cv = fmaf(2.44140625e-4f, crA[r] + crB[r], hh[r]); \
                if (cv > bests[qg]) { bests[qg] = cv; besti[qg] = kb + r; }    \
            }                                                                 \
        }                                                                     \
        __builtin_amdgcn_s_setprio(0);                                        \
    }

#define WAIT2 asm volatile("s_waitcnt vmcnt(2)" ::: "memory")
#define WAIT4 asm volatile("s_waitcnt vmcnt(4)" ::: "memory")
#define WAIT0 asm volatile("s_waitcnt vmcnt(0)" ::: "memory")
#define BAR   __builtin_amdgcn_s_barrier()

// step S: WAIT2 retires stage(S+1) (S+2 stays in flight); barrier makes it
// cross-wave; issue stage(S+3); ds_read tile S+1 into the alternate reg set
// while computing tile S from the current set.
#define STEP(S, STGB, PFB, C0, C1, C2, C3, CE, P0, P1, P2, P3, PE)            \
    {   WAIT2; BAR;                                                           \
        STAGE((S) + 3, STGB)                                                  \
        PREF(2 * ((S) + 1) + wk, PFB, P0, P1, P2, P3, PE)                     \
        COMP(2 * (S) + wk, C0, C1, C2, C3, CE)                                \
    }

    // vmcnt ledger (ops): me2l=1, each STAGE=2.
    // prologue: issue me2l, S0, S1, S2 (7 outstanding); WAIT4 retires
    // me2l+S0; BAR; ds_read tile-pair 0. Steady state at step S entry:
    // outstanding {stage(S+1), stage(S+2)} = 4 ops -> WAIT2 retires S+1.
    half8 fE0, fE1, fE2, fE3, fO0, fO1, fO2, fO3;
    f32x4 eE, eO;

    STAGE(0, 0)
    STAGE(1, 1)
    STAGE(2, 2)
    WAIT4; BAR;
    PREF(wk, 0, fE0, fE1, fE2, fE3, eE)       // tile-pair 0, my parity

    #pragma unroll 1
    for (int s0 = 0; s0 < 28; s0 += 4) {
        STEP(s0 + 0, 3, 1, fE0, fE1, fE2, fE3, eE, fO0, fO1, fO2, fO3, eO)
        STEP(s0 + 1, 0, 2, fO0, fO1, fO2, fO3, eO, fE0, fE1, fE2, fE3, eE)
        STEP(s0 + 2, 1, 3, fE0, fE1, fE2, fE3, eE, fO0, fO1, fO2, fO3, eO)
        STEP(s0 + 3, 2, 0, fO0, fO1, fO2, fO3, eO, fE0, fE1, fE2, fE3, eE)
    }
    // S=28: last stage (31 -> buf 3)
    STEP(28, 3, 1, fE0, fE1, fE2, fE3, eE, fO0, fO1, fO2, fO3, eO)
    // S=29: outstanding {S30,S31}; WAIT2 retires S30 -> prefetch pair 30
    WAIT2; BAR;
    PREF(2 * 30 + wk, 2, fE0, fE1, fE2, fE3, eE)
    COMP(2 * 29 + wk, fO0, fO1, fO2, fO3, eO)
    // S=30: outstanding {S31}; WAIT0 retires it -> prefetch pair 31
    WAIT0; BAR;
    PREF(2 * 31 + wk, 3, fO0, fO1, fO2, fO3, eO)
    COMP(2 * 30 + wk, fE0, fE1, fE2, fE3, eE)
    // S=31: compute only
    COMP(2 * 31 + wk, fO0, fO1, fO2, fO3, eO)

    besti[0] += lq * 4;     // full code index = kt*16 + lq*4 + r
    besti[1] += lq * 4;
    besti[2] += lq * 4;
    besti[3] += lq * 4;

    // ---- wave-internal argmax reduce across the 4 row-quads ----
    #pragma unroll
    for (int qg = 0; qg < 4; ++qg) {
        #pragma unroll
        for (int msk = 16; msk <= 32; msk <<= 1) {
            const float ov = __shfl_xor(bests[qg], msk, 64);
            const int   oi = __shfl_xor(besti[qg], msk, 64);
            if (ov > bests[qg] || (ov == bests[qg] && oi < besti[qg])) {
                bests[qg] = ov; besti[qg] = oi;
            }
        }
    }

    // ---- cross-wave combine: wk=1 publishes, wk=0 merges (x2 in regs) ----
    __syncthreads();    // all waves out of the buffers; bv/bj space free
    if (wk == 1 && lq == 0) {
        #pragma unroll
        for (int qg = 0; qg < 4; ++qg) {
            const int q = wq * 64 + qg * 16 + ln;
            bv[q] = bests[qg];
            bj[q] = besti[qg];
        }
    }
    __syncthreads();

    float lsum = 0.f;
    if (wk == 0 && lq == 0) {
        #pragma unroll
        for (int qg = 0; qg < 4; ++qg) {
            const int q = wq * 64 + qg * 16 + ln;
            const float ov = bv[q];
            const int   oi = bj[q];
            if (ov > bests[qg] || (ov == bests[qg] && oi < besti[qg])) {
                bests[qg] = ov; besti[qg] = oi;
            }
            idxs[q] = besti[qg];
            out[IDX_OFF + n0 + q] = (float)besti[qg];
            // d = -2*s ; loss term = d + ||x||^2
            lsum += fmaf(-2.0f, bests[qg], x2r[qg]);
        }
    }
    #pragma unroll
    for (int off = 32; off > 0; off >>= 1) lsum += __shfl_down(lsum, off, 64);
    if (lane == 0) wsum[w] = lsum;
    __syncthreads();    // idxs + wsum visible
    if (tid == 0) {
        const float s = wsum[0] + wsum[1] + wsum[2] + wsum[3];
        atomicAdd(&out[LOSS_OFF],     s * (1.0f  / (float)QELEMS));
        atomicAdd(&out[LOSS_OFF + 1], s * (0.25f / (float)QELEMS));
    }

    // ---- epilogue: gather code rows into LDS (Q @ 2048), transpose-write ----
    {
        const int q  = tid >> 1;
        const int hf = tid & 1;
        const float* er = emb + (size_t)idxs[q] * CDIM + hf * 32;
        #pragma unroll
        for (int j = 0; j < 8; ++j) {
            const float4 v = *(const float4*)(er + 4 * j);
            *(float4*)(&Q[q][hf * 32 + 4 * j]) = v;
        }
    }
    __syncthreads();
    {
        const int nl = tid & 127;
        const int cb = tid >> 7;
        #pragma unroll 8
        for (int r = 0; r < 32; ++r) {
            const int c = 2 * r + cb;
            outb[(size_t)c * THW + nl] = Q[nl][c];
        }
    }
#undef STAGE
#undef PREF
#undef COMP
#undef WAIT2
#undef WAIT4
#undef WAIT0
#undef BAR
#undef STEP
}

extern "C" void kernel_launch(void* const* d_in, const int* in_sizes, int n_in,
                              void* d_out, int out_size, void* d_ws, size_t ws_size,
                              hipStream_t stream) {
    const float* in  = (const float*)d_in[0];   // (8, 64, 16, 32, 32) fp32
    const float* emb = (const float*)d_in[1];   // (1024, 64) fp32
    float* out = (float*)d_out;
    _Float16* Ef   = (_Float16*)d_ws;                       // 64 tiles * 4 KB = 256 KB
    float*    me2h = (float*)((char*)d_ws + 262144);        // 1024 floats = -0.5*||e||^2

    vq_prep<<<KDIM / 16, 256, 0, stream>>>(emb, Ef, me2h, out);
    vq_main<<<NTOT / BN, 256, 0, stream>>>(in, emb, Ef, me2h, out);
}